// Round 8
// baseline (424.171 us; speedup 1.0000x reference)
//
#include <hip/hip_runtime.h>
#include <math.h>

#define B_ 2
#define H_ 48
#define W_ 48
#define C_ 96
#define D_ 192
#define L_ 2304   // H_*W_
#define K_ 4
#define NS 32     // D_STATE
#define RK 6      // DT_RANK
#define CD 70     // RK + 2*NS

#define NC 16         // scan chunks
#define CL (L_/NC)    // 144 steps per chunk
#define NCH (B_*K_*D_)// 1536 chains
#define LOG2E 1.44269504088896f

__device__ __forceinline__ float fexp2(float x) {
#if __has_builtin(__builtin_amdgcn_exp2f)
    return __builtin_amdgcn_exp2f(x);
#else
    return __expf(x * 0.69314718055994531f);
#endif
}

// workspace offsets (floats)
#define BDL (B_*D_*L_)                    // 884736
#define OFF_Z      0                      // z stored (b, l, d)
#define OFF_XPRE   (OFF_Z    + BDL)
#define OFF_XHW    (OFF_XPRE + BDL)
#define OFF_XWH    (OFF_XHW  + BDL)
#define OFF_DELTA  (OFF_XWH  + BDL)      // size B*K*D*L, layout (b,k,d,l)
#define OFF_BS     (OFF_DELTA+ B_*K_*D_*L_)  // (b,k,n,l)  n-major
#define OFF_CS     (OFF_BS   + B_*K_*L_*NS)  // (b,k,n,l)
#define OFF_YS     (OFF_CS   + B_*K_*L_*NS)  // (b,k,l,d)
#define OFF_YF     (OFF_YS   + B_*K_*L_*D_)  // B*L*D (only H0 lives here)

// H0 scratch: NCH*NC*NS = 786432 <= YF region (884736)
#define OFF_H0     OFF_YF

// ---------------- K1: in_proj GEMM ------------------------------------------
// grid 576 = b(2) * ltile32(72) * es(4); es 0,1 -> xpre (b,d,pos); 2,3 -> z (b,l,d)
__global__ __launch_bounds__(256) void k1_inproj(const float* __restrict__ x,
        const float* __restrict__ w, float* __restrict__ ws) {
    __shared__ __align__(16) float Xs[24*128];   // [cq][l*4+sub], 32 l
    int blk = blockIdx.x;
    int b = blk / 288;
    int rem = blk % 288;
    int l0 = (rem >> 2) * 32;
    int es = rem & 3;
    int tid = threadIdx.x;
    const float4* xs4 = (const float4*)(x + (size_t)(b*L_ + l0)*C_);
    #pragma unroll
    for (int it = 0; it < 3; ++it) {
        int i4 = it*256 + tid;        // 768 float4 = 3072 floats
        float4 v = xs4[i4];
        int idx4 = i4*4;
        int p = idx4 / 96, c = idx4 % 96;   // c % 4 == 0
        *(float4*)&Xs[(c>>2)*128 + p*4] = v;
    }
    __syncthreads();
    int l = tid & 31, eg = tid >> 5;
    int pos = l0 + l;
    float acc[12];
    #pragma unroll
    for (int i = 0; i < 12; ++i) acc[i] = 0.f;
    const float4* wp[12];
    #pragma unroll
    for (int i = 0; i < 12; ++i) {
        int e = es*96 + eg*12 + i;
        wp[i] = (const float4*)(w + (size_t)e*96);
    }
    for (int q = 0; q < 24; ++q) {
        float4 xr = *(const float4*)&Xs[q*128 + l*4];
        #pragma unroll
        for (int i = 0; i < 12; ++i) {
            float4 wv = wp[i][q];
            acc[i] += xr.x*wv.x + xr.y*wv.y + xr.z*wv.z + xr.w*wv.w;
        }
    }
    if (es < 2) {
        float* xpre = ws + OFF_XPRE;
        #pragma unroll
        for (int i = 0; i < 12; ++i) {
            int e = es*96 + eg*12 + i;
            xpre[(size_t)(b*D_ + e)*L_ + pos] = acc[i];
        }
    } else {
        float* zp = ws + OFF_Z + (size_t)(b*L_ + pos)*D_ + (es-2)*96 + eg*12;
        #pragma unroll
        for (int q = 0; q < 3; ++q)
            *(float4*)&zp[q*4] = make_float4(acc[q*4], acc[q*4+1], acc[q*4+2], acc[q*4+3]);
    }
}

// ---------------- K2: depthwise 3x3 conv + SiLU, half-image blocks ----------
__global__ __launch_bounds__(256) void k2_conv(const float* __restrict__ cw,
        const float* __restrict__ cb, float* __restrict__ ws) {
    __shared__ float img[26*48];
    __shared__ float res[24*49];     // padded for transpose read
    int blk = blockIdx.x;            // 768 = bd*2 + half
    int bd = blk >> 1;
    int half = blk & 1;
    int d = bd % D_;
    int hh0 = half * 24;
    int tid = threadIdx.x;
    const float* xp = ws + OFF_XPRE + (size_t)bd*L_;
    for (int it = 0; it < 5; ++it) {
        int idx = it*256 + tid;
        if (idx < 26*48) {
            int gr = hh0 - 1 + idx/48;
            img[idx] = (gr >= 0 && gr < H_) ? xp[gr*48 + idx%48] : 0.f;
        }
    }
    float wr[9];
    #pragma unroll
    for (int j = 0; j < 9; ++j) wr[j] = cw[d*9 + j];
    float bias = cb[d];
    __syncthreads();
    float* hw = ws + OFF_XHW + (size_t)bd*L_ + hh0*48;
    for (int it = 0; it < 5; ++it) {
        int idx = it*256 + tid;
        if (idx < 24*48) {
            int r = idx/48, w0 = idx%48;
            float acc = bias;
            #pragma unroll
            for (int kh = 0; kh < 3; ++kh) {
                #pragma unroll
                for (int kw = 0; kw < 3; ++kw) {
                    int iw = w0 + kw - 1;
                    if (iw >= 0 && iw < W_)
                        acc = fmaf(img[(r+kh)*48 + iw], wr[kh*3 + kw], acc);
                }
            }
            float v = acc / (1.f + __expf(-acc));
            hw[idx] = v;
            res[r*49 + w0] = v;
        }
    }
    __syncthreads();
    float* wh = ws + OFF_XWH + (size_t)bd*L_;
    for (int it = 0; it < 5; ++it) {
        int idx = it*256 + tid;
        if (idx < 24*48) {
            int w0 = idx/24, r = idx%24;
            wh[w0*48 + hh0 + r] = res[r*49 + w0];
        }
    }
}

// ---------------- K3: x_proj matvec + dt_proj + softplus + B/C split --------
// grid 1152 = b(2) * k(4) * ltile16(144); Bs/Cs written (b,k,n,l)
__global__ __launch_bounds__(256) void k3_xproj(const float* __restrict__ xpw,
        const float* __restrict__ dtw, const float* __restrict__ dtb,
        float* __restrict__ ws) {
    __shared__ __align__(16) float Xs[48*64];    // [dq][l*4+sub], 16 l
    __shared__ float xd[CD*17];                  // [c][l], pad 17
    int blk = blockIdx.x;
    int b = blk / 576;
    int rem = blk % 576;
    int k = rem / 144;
    int l0 = (rem % 144) * 16;
    int tid = threadIdx.x;
    const float* src = ws + ((k & 1) ? OFF_XWH : OFF_XHW);
    bool flip = (k >= 2);
    #pragma unroll
    for (int it = 0; it < 12; ++it) {
        int idx = it*256 + tid;
        int d = idx >> 4, l = idx & 15;
        int pos = flip ? (L_ - 1 - (l0 + l)) : (l0 + l);
        Xs[(d>>2)*64 + l*4 + (d&3)] = src[(size_t)(b*D_ + d)*L_ + pos];
    }
    __syncthreads();
    int l = tid & 15, cg = tid >> 4;    // 16 l x 16 cg
    {
        float acc[5] = {0.f, 0.f, 0.f, 0.f, 0.f};
        const float4* wp[5];
        #pragma unroll
        for (int i = 0; i < 5; ++i) {
            int c = cg + 16*i;
            if (c >= CD) c = 0;          // guard OOB; result masked on write
            wp[i] = (const float4*)(xpw + ((size_t)k*CD + c)*D_);
        }
        for (int q = 0; q < 48; ++q) {
            float4 xr = *(const float4*)&Xs[q*64 + l*4];
            #pragma unroll
            for (int i = 0; i < 5; ++i) {
                float4 wv = wp[i][q];
                acc[i] += xr.x*wv.x + xr.y*wv.y + xr.z*wv.z + xr.w*wv.w;
            }
        }
        #pragma unroll
        for (int i = 0; i < 5; ++i) {
            int c = cg + 16*i;
            if (c < CD) xd[c*17 + l] = acc[i];
        }
    }
    __syncthreads();
    {   // dt_proj + softplus -> deltas (b,k,d,l)
        float r[6];
        #pragma unroll
        for (int rr = 0; rr < 6; ++rr) r[rr] = xd[rr*17 + l];
        float* dout = ws + OFF_DELTA + (size_t)(b*K_ + k)*D_*L_;
        int dg = tid >> 4;
        for (int i = 0; i < 12; ++i) {
            int d = dg*12 + i;
            const float* wdt = dtw + ((size_t)k*D_ + d)*6;
            float acc = dtb[k*D_ + d];
            #pragma unroll
            for (int rr = 0; rr < 6; ++rr) acc = fmaf(r[rr], wdt[rr], acc);
            float sp = fmaxf(acc, 0.f) + log1pf(__expf(-fabsf(acc)));
            dout[(size_t)d*L_ + l0 + l] = sp;
        }
    }
    {   // Bs/Cs -> (b,k,n,l): lane = l (coalesced 64B rows per n)
        float* Bb = ws + OFF_BS + (size_t)(b*K_ + k)*NS*L_;
        float* Cb = ws + OFF_CS + (size_t)(b*K_ + k)*NS*L_;
        int ll = tid & 15, nh = tid >> 4;
        #pragma unroll
        for (int j = 0; j < 2; ++j) {
            int n = nh + 16*j;
            Bb[(size_t)n*L_ + l0 + ll] = xd[(RK + n)*17 + ll];
            Cb[(size_t)n*L_ + l0 + ll] = xd[(RK + NS + n)*17 + ll];
        }
    }
}

// ---------------- K4a: local chunk scan + in-LDS combine -> H0 --------------
// grid 1536 = bk(8) * d(192); 512 thr = 16 chunks x 32 states; 1 chain/lane
__global__ __launch_bounds__(512) void k4a_local(const float* __restrict__ Alogs,
        float* __restrict__ ws) {
    __shared__ float Pl[NC][NS];
    __shared__ float Hl[NC][NS];
    int blk = blockIdx.x;
    int d = blk % D_;
    int bk = blk / D_;
    int b = bk >> 2, k = bk & 3;
    int c = threadIdx.x >> 5;
    int n = threadIdx.x & 31;
    float a2 = -__expf(Alogs[((size_t)k*D_ + d)*NS + n]) * LOG2E;
    const float* dptr = ws + OFF_DELTA + (size_t)(bk*D_ + d)*L_ + c*CL;
    const float* ubase = ws + ((k & 1) ? OFF_XWH : OFF_XHW) + (size_t)(b*D_ + d)*L_;
    const float* Bp = ws + OFF_BS + ((size_t)bk*NS + n)*L_ + c*CL;
    bool flip = (k >= 2);
    float h = 0.f, sd = 0.f;
    for (int lb = 0; lb < CL; lb += 4) {
        float4 d4 = *(const float4*)(dptr + lb);
        float4 b4 = *(const float4*)(Bp + lb);
        float4 t4;
        if (!flip) {
            t4 = *(const float4*)(ubase + c*CL + lb);
        } else {
            float4 r = *(const float4*)(ubase + (L_ - 4) - (c*CL + lb));
            t4 = make_float4(r.w, r.z, r.y, r.x);
        }
        float dl[4] = {d4.x, d4.y, d4.z, d4.w};
        float uu[4] = {t4.x, t4.y, t4.z, t4.w};
        float bb[4] = {b4.x, b4.y, b4.z, b4.w};
        #pragma unroll
        for (int j = 0; j < 4; ++j) {
            float e = fexp2(dl[j]*a2);
            h = fmaf(h, e, dl[j]*uu[j]*bb[j]);
            sd += dl[j];
        }
    }
    Pl[c][n] = fexp2(a2*sd);   // product of dA over chunk == exp(a * sum delta)
    Hl[c][n] = h;
    __syncthreads();
    if (threadIdx.x < NS) {    // serial combine over chunks; n = threadIdx.x
        float hh = 0.f;
        #pragma unroll
        for (int cc = 0; cc < NC; ++cc) {
            float p  = Pl[cc][n];
            float hf = Hl[cc][n];
            Pl[cc][n] = hh;    // overwrite with h0 for chunk cc
            hh = fmaf(hh, p, hf);
        }
    }
    __syncthreads();
    // coalesced H0 write: layout (chain, c, n), linear in tid
    ws[OFF_H0 + (size_t)(bk*D_ + d)*NC*NS + threadIdx.x] = Pl[c][n];
}

// ---------------- K4c: replay from true h0; batch-4 reduce; coalesced write -
// grid 1536 = bk(8) * c(16) * dg(12); 512 thr = 16 subwaves(d) x 32 states
__global__ __launch_bounds__(512) void k4c_scan(const float* __restrict__ Alogs,
        const float* __restrict__ Dsp, float* __restrict__ ws) {
    __shared__ float yld[CL*17];     // [l][d], stride 17 -> conflict-free
    int blk = blockIdx.x;
    int dg = blk % 12;
    int c  = (blk / 12) % NC;
    int bk = blk / (12*NC);
    int b = bk >> 2, k = bk & 3;
    int sw = threadIdx.x >> 5;
    int n  = threadIdx.x & 31;
    int d = dg*16 + sw;
    float a2 = -__expf(Alogs[((size_t)k*D_ + d)*NS + n]) * LOG2E;
    float dc32 = Dsp[k*D_ + d] * (1.f/32.f);
    const float* dptr = ws + OFF_DELTA + (size_t)(bk*D_ + d)*L_ + c*CL;
    const float* ubase = ws + ((k & 1) ? OFF_XWH : OFF_XHW) + (size_t)(b*D_ + d)*L_;
    const float* Bp = ws + OFF_BS + ((size_t)bk*NS + n)*L_ + c*CL;
    const float* Cp = ws + OFF_CS + ((size_t)bk*NS + n)*L_ + c*CL;
    bool flip = (k >= 2);
    float h = ws[OFF_H0 + (size_t)(bk*D_ + d)*NC*NS + c*NS + n];
    int g = n >> 3;
    int off = ((g & 1) << 1) | (g >> 1);   // lane-group -> l-offset [0,2,1,3]
    for (int lb = 0; lb < CL; lb += 4) {
        float4 d4 = *(const float4*)(dptr + lb);
        float4 b4 = *(const float4*)(Bp + lb);
        float4 c4 = *(const float4*)(Cp + lb);
        float4 t4;
        if (!flip) {
            t4 = *(const float4*)(ubase + c*CL + lb);
        } else {
            float4 r = *(const float4*)(ubase + (L_ - 4) - (c*CL + lb));
            t4 = make_float4(r.w, r.z, r.y, r.x);
        }
        float dl[4] = {d4.x, d4.y, d4.z, d4.w};
        float uu[4] = {t4.x, t4.y, t4.z, t4.w};
        float bb[4] = {b4.x, b4.y, b4.z, b4.w};
        float cc[4] = {c4.x, c4.y, c4.z, c4.w};
        float y[4];
        #pragma unroll
        for (int j = 0; j < 4; ++j) {
            float e = fexp2(dl[j]*a2);
            h = fmaf(h, e, dl[j]*uu[j]*bb[j]);
            // D*u/32 folded into every lane's y: 32-lane tree-sum restores D*u
            y[j] = fmaf(h, cc[j], dc32*uu[j]);
        }
        // shared butterfly: 4 values reduced across 32 lanes
        #pragma unroll
        for (int j = 0; j < 4; ++j) y[j] += __shfl_xor(y[j], 16);
        float z0 = (n & 16) ? y[1] : y[0];
        float z1 = (n & 16) ? y[3] : y[2];
        z0 += __shfl_xor(z0, 8);
        z1 += __shfl_xor(z1, 8);
        float wv = (n & 8) ? z1 : z0;
        wv += __shfl_xor(wv, 4);
        wv += __shfl_xor(wv, 2);
        wv += __shfl_xor(wv, 1);
        if ((n & 7) == 0) yld[(lb + off)*17 + sw] = wv;
    }
    __syncthreads();
    float* ysp = ws + OFF_YS + ((size_t)bk*L_ + c*CL)*D_ + dg*16;
    for (int it = 0; it < 5; ++it) {
        int idx = it*512 + threadIdx.x;
        if (idx < CL*16) {
            int l = idx >> 4, dd = idx & 15;
            ysp[(size_t)l*D_ + dd] = yld[l*17 + dd];
        }
    }
}

// ---------------- K56: merge + LayerNorm + SiLU gate + out_proj + residual --
// grid 288 = b(2) * ltile16(144); 256 thr
__global__ __launch_bounds__(256) void k56_fused(const float* __restrict__ lnw,
        const float* __restrict__ lnb, const float* __restrict__ w,
        const float* __restrict__ xin, float* __restrict__ out,
        const float* __restrict__ ws) {
    __shared__ __align__(16) float YsT[16*196];  // [pos][d], stride 196
    __shared__ float psum[16][17], psq[16][17];
    __shared__ float outT[16*97];
    int blk = blockIdx.x;
    int b = blk / 144;
    int l0 = (blk % 144) * 16;
    int tid = threadIdx.x;
    {   // phase A: 16 pos x 16 dgroups, 12 d each
        int p = tid >> 4, dg = tid & 15;
        int pos = l0 + p;
        int hh = pos / W_, w0 = pos % W_;
        int poswh = w0*H_ + hh;
        const float* ysb = ws + OFF_YS + (size_t)b*K_*L_*D_;
        const float* r0 = ysb + (size_t)(0*L_ + pos)*D_;
        const float* r1 = ysb + (size_t)(1*L_ + poswh)*D_;
        const float* r2 = ysb + (size_t)(2*L_ + (L_-1-pos))*D_;
        const float* r3 = ysb + (size_t)(3*L_ + (L_-1-poswh))*D_;
        float yv[12];
        float s = 0.f, sq = 0.f;
        #pragma unroll
        for (int i = 0; i < 12; i += 4) {
            int d = dg*12 + i;
            float4 v0 = *(const float4*)(r0 + d);
            float4 v1 = *(const float4*)(r1 + d);
            float4 v2 = *(const float4*)(r2 + d);
            float4 v3 = *(const float4*)(r3 + d);
            float y0 = v0.x+v1.x+v2.x+v3.x;
            float y1 = v0.y+v1.y+v2.y+v3.y;
            float y2 = v0.z+v1.z+v2.z+v3.z;
            float y3 = v0.w+v1.w+v2.w+v3.w;
            yv[i]=y0; yv[i+1]=y1; yv[i+2]=y2; yv[i+3]=y3;
            s += y0+y1+y2+y3;
            sq += y0*y0+y1*y1+y2*y2+y3*y3;
        }
        psum[p][dg] = s; psq[p][dg] = sq;
        __syncthreads();
        float su = 0.f, ssq = 0.f;
        #pragma unroll
        for (int j = 0; j < 16; ++j) { su += psum[p][j]; ssq += psq[p][j]; }
        float mu  = su * (1.f/192.f);
        float var = ssq * (1.f/192.f) - mu*mu;
        float rs  = rsqrtf(var + 1e-5f);
        const float* zp = ws + OFF_Z + (size_t)(b*L_ + pos)*D_;
        #pragma unroll
        for (int i = 0; i < 12; i += 4) {
            int d = dg*12 + i;
            float4 o;
            float* oo = (float*)&o;
            #pragma unroll
            for (int jj = 0; jj < 4; ++jj) {
                float yn = (yv[i+jj] - mu)*rs*lnw[d+jj] + lnb[d+jj];
                float zv = zp[d+jj];
                float sz = zv / (1.f + __expf(-zv));
                oo[jj] = yn * sz;
            }
            *(float4*)&YsT[p*196 + d] = o;
        }
    }
    __syncthreads();
    {   // phase B: GEMM 16 l x 96 c, acc[6] per thread
        int l = tid & 15, cg = tid >> 4;
        float acc[6] = {0.f,0.f,0.f,0.f,0.f,0.f};
        const float4* wp[6];
        #pragma unroll
        for (int i = 0; i < 6; ++i)
            wp[i] = (const float4*)(w + (size_t)(cg*6 + i)*D_);
        for (int q = 0; q < 48; ++q) {
            float4 xr = *(const float4*)&YsT[l*196 + q*4];
            #pragma unroll
            for (int i = 0; i < 6; ++i) {
                float4 wv = wp[i][q];
                acc[i] += xr.x*wv.x + xr.y*wv.y + xr.z*wv.z + xr.w*wv.w;
            }
        }
        #pragma unroll
        for (int i = 0; i < 6; ++i) outT[l*97 + cg*6 + i] = acc[i];
    }
    __syncthreads();
    #pragma unroll
    for (int it = 0; it < 6; ++it) {
        int idx = it*256 + tid;      // 16*96 = 1536
        int p = idx / 96, cc = idx % 96;
        size_t o = (size_t)(b*L_ + l0 + p)*C_ + cc;
        out[o] = xin[o] + outT[p*97 + cc];
    }
}

extern "C" void kernel_launch(void* const* d_in, const int* in_sizes, int n_in,
                              void* d_out, int out_size, void* d_ws, size_t ws_size,
                              hipStream_t stream) {
    const float* x        = (const float*)d_in[0];
    const float* in_proj  = (const float*)d_in[1];
    const float* conv_w   = (const float*)d_in[2];
    const float* conv_b   = (const float*)d_in[3];
    const float* x_proj_w = (const float*)d_in[4];
    const float* dt_w     = (const float*)d_in[5];
    const float* dt_b     = (const float*)d_in[6];
    const float* A_logs   = (const float*)d_in[7];
    const float* Ds       = (const float*)d_in[8];
    const float* ln_w     = (const float*)d_in[9];
    const float* ln_b     = (const float*)d_in[10];
    const float* out_w    = (const float*)d_in[11];
    float* out = (float*)d_out;
    float* ws  = (float*)d_ws;

    k1_inproj <<<576,  256, 0, stream>>>(x, in_proj, ws);
    k2_conv   <<<768,  256, 0, stream>>>(conv_w, conv_b, ws);
    k3_xproj  <<<1152, 256, 0, stream>>>(x_proj_w, dt_w, dt_b, ws);
    k4a_local <<<NCH,  512, 0, stream>>>(A_logs, ws);
    k4c_scan  <<<1536, 512, 0, stream>>>(A_logs, Ds, ws);
    k56_fused <<<288,  256, 0, stream>>>(ln_w, ln_b, out_w, x, out, ws);
}

// Round 9
// 288.664 us; speedup vs baseline: 1.4694x; 1.4694x over previous
//
#include <hip/hip_runtime.h>
#include <math.h>

#define B_ 2
#define H_ 48
#define W_ 48
#define C_ 96
#define D_ 192
#define L_ 2304   // H_*W_
#define K_ 4
#define NS 32     // D_STATE
#define RK 6      // DT_RANK
#define CD 70     // RK + 2*NS

#define NC 16         // scan chunks
#define CL (L_/NC)    // 144 steps per chunk
#define NCH (B_*K_*D_)// 1536 chains
#define LOG2E 1.44269504088896f

__device__ __forceinline__ float fexp2(float x) {
#if __has_builtin(__builtin_amdgcn_exp2f)
    return __builtin_amdgcn_exp2f(x);
#else
    return __expf(x * 0.69314718055994531f);
#endif
}

// workspace offsets (floats)
#define BDL (B_*D_*L_)                    // 884736
#define OFF_Z      0                      // z stored (b, l, d)
#define OFF_XPRE   (OFF_Z    + BDL)
#define OFF_XHW    (OFF_XPRE + BDL)
#define OFF_XWH    (OFF_XHW  + BDL)
#define OFF_DELTA  (OFF_XWH  + BDL)      // size B*K*D*L, layout (b,k,d,l)
#define OFF_BS     (OFF_DELTA+ B_*K_*D_*L_)  // (b,k,l,n)  l-major: lane-coalesced
#define OFF_CS     (OFF_BS   + B_*K_*L_*NS)  // (b,k,l,n)
#define OFF_YS     (OFF_CS   + B_*K_*L_*NS)  // (b,k,l,d)
#define OFF_YF     (OFF_YS   + B_*K_*L_*D_)  // B*L*D (only H0 lives here)

// H0 scratch: NCH*NC*NS = 786432 <= YF region (884736)
#define OFF_H0     OFF_YF

// ---------------- K1: in_proj GEMM ------------------------------------------
// grid 576 = b(2) * ltile32(72) * es(4); es 0,1 -> xpre (b,d,pos); 2,3 -> z (b,l,d)
__global__ __launch_bounds__(256) void k1_inproj(const float* __restrict__ x,
        const float* __restrict__ w, float* __restrict__ ws) {
    __shared__ __align__(16) float Xs[24*128];   // [cq][l*4+sub], 32 l
    int blk = blockIdx.x;
    int b = blk / 288;
    int rem = blk % 288;
    int l0 = (rem >> 2) * 32;
    int es = rem & 3;
    int tid = threadIdx.x;
    const float4* xs4 = (const float4*)(x + (size_t)(b*L_ + l0)*C_);
    #pragma unroll
    for (int it = 0; it < 3; ++it) {
        int i4 = it*256 + tid;        // 768 float4 = 3072 floats
        float4 v = xs4[i4];
        int idx4 = i4*4;
        int p = idx4 / 96, c = idx4 % 96;   // c % 4 == 0
        *(float4*)&Xs[(c>>2)*128 + p*4] = v;
    }
    __syncthreads();
    int l = tid & 31, eg = tid >> 5;
    int pos = l0 + l;
    float acc[12];
    #pragma unroll
    for (int i = 0; i < 12; ++i) acc[i] = 0.f;
    const float4* wp[12];
    #pragma unroll
    for (int i = 0; i < 12; ++i) {
        int e = es*96 + eg*12 + i;
        wp[i] = (const float4*)(w + (size_t)e*96);
    }
    for (int q = 0; q < 24; ++q) {
        float4 xr = *(const float4*)&Xs[q*128 + l*4];
        #pragma unroll
        for (int i = 0; i < 12; ++i) {
            float4 wv = wp[i][q];
            acc[i] += xr.x*wv.x + xr.y*wv.y + xr.z*wv.z + xr.w*wv.w;
        }
    }
    if (es < 2) {
        float* xpre = ws + OFF_XPRE;
        #pragma unroll
        for (int i = 0; i < 12; ++i) {
            int e = es*96 + eg*12 + i;
            xpre[(size_t)(b*D_ + e)*L_ + pos] = acc[i];
        }
    } else {
        float* zp = ws + OFF_Z + (size_t)(b*L_ + pos)*D_ + (es-2)*96 + eg*12;
        #pragma unroll
        for (int q = 0; q < 3; ++q)
            *(float4*)&zp[q*4] = make_float4(acc[q*4], acc[q*4+1], acc[q*4+2], acc[q*4+3]);
    }
}

// ---------------- K2: depthwise 3x3 conv + SiLU, half-image blocks ----------
__global__ __launch_bounds__(256) void k2_conv(const float* __restrict__ cw,
        const float* __restrict__ cb, float* __restrict__ ws) {
    __shared__ float img[26*48];
    __shared__ float res[24*49];     // padded for transpose read
    int blk = blockIdx.x;            // 768 = bd*2 + half
    int bd = blk >> 1;
    int half = blk & 1;
    int d = bd % D_;
    int hh0 = half * 24;
    int tid = threadIdx.x;
    const float* xp = ws + OFF_XPRE + (size_t)bd*L_;
    for (int it = 0; it < 5; ++it) {
        int idx = it*256 + tid;
        if (idx < 26*48) {
            int gr = hh0 - 1 + idx/48;
            img[idx] = (gr >= 0 && gr < H_) ? xp[gr*48 + idx%48] : 0.f;
        }
    }
    float wr[9];
    #pragma unroll
    for (int j = 0; j < 9; ++j) wr[j] = cw[d*9 + j];
    float bias = cb[d];
    __syncthreads();
    float* hw = ws + OFF_XHW + (size_t)bd*L_ + hh0*48;
    for (int it = 0; it < 5; ++it) {
        int idx = it*256 + tid;
        if (idx < 24*48) {
            int r = idx/48, w0 = idx%48;
            float acc = bias;
            #pragma unroll
            for (int kh = 0; kh < 3; ++kh) {
                #pragma unroll
                for (int kw = 0; kw < 3; ++kw) {
                    int iw = w0 + kw - 1;
                    if (iw >= 0 && iw < W_)
                        acc = fmaf(img[(r+kh)*48 + iw], wr[kh*3 + kw], acc);
                }
            }
            float v = acc / (1.f + __expf(-acc));
            hw[idx] = v;
            res[r*49 + w0] = v;
        }
    }
    __syncthreads();
    float* wh = ws + OFF_XWH + (size_t)bd*L_;
    for (int it = 0; it < 5; ++it) {
        int idx = it*256 + tid;
        if (idx < 24*48) {
            int w0 = idx/24, r = idx%24;
            wh[w0*48 + hh0 + r] = res[r*49 + w0];
        }
    }
}

// ---------------- K3: x_proj matvec + dt_proj + softplus + B/C split --------
// grid 1152 = b(2) * k(4) * ltile16(144); Bs/Cs written (b,k,l,n)
__global__ __launch_bounds__(256) void k3_xproj(const float* __restrict__ xpw,
        const float* __restrict__ dtw, const float* __restrict__ dtb,
        float* __restrict__ ws) {
    __shared__ __align__(16) float Xs[48*64];    // [dq][l*4+sub], 16 l
    __shared__ float xd[CD*17];                  // [c][l], pad 17
    int blk = blockIdx.x;
    int b = blk / 576;
    int rem = blk % 576;
    int k = rem / 144;
    int l0 = (rem % 144) * 16;
    int tid = threadIdx.x;
    const float* src = ws + ((k & 1) ? OFF_XWH : OFF_XHW);
    bool flip = (k >= 2);
    #pragma unroll
    for (int it = 0; it < 12; ++it) {
        int idx = it*256 + tid;
        int d = idx >> 4, l = idx & 15;
        int pos = flip ? (L_ - 1 - (l0 + l)) : (l0 + l);
        Xs[(d>>2)*64 + l*4 + (d&3)] = src[(size_t)(b*D_ + d)*L_ + pos];
    }
    __syncthreads();
    int l = tid & 15, cg = tid >> 4;    // 16 l x 16 cg
    {
        float acc[5] = {0.f, 0.f, 0.f, 0.f, 0.f};
        const float4* wp[5];
        #pragma unroll
        for (int i = 0; i < 5; ++i) {
            int c = cg + 16*i;
            if (c >= CD) c = 0;          // guard OOB; result masked on write
            wp[i] = (const float4*)(xpw + ((size_t)k*CD + c)*D_);
        }
        for (int q = 0; q < 48; ++q) {
            float4 xr = *(const float4*)&Xs[q*64 + l*4];
            #pragma unroll
            for (int i = 0; i < 5; ++i) {
                float4 wv = wp[i][q];
                acc[i] += xr.x*wv.x + xr.y*wv.y + xr.z*wv.z + xr.w*wv.w;
            }
        }
        #pragma unroll
        for (int i = 0; i < 5; ++i) {
            int c = cg + 16*i;
            if (c < CD) xd[c*17 + l] = acc[i];
        }
    }
    __syncthreads();
    {   // dt_proj + softplus -> deltas (b,k,d,l)
        float r[6];
        #pragma unroll
        for (int rr = 0; rr < 6; ++rr) r[rr] = xd[rr*17 + l];
        float* dout = ws + OFF_DELTA + (size_t)(b*K_ + k)*D_*L_;
        int dg = tid >> 4;
        for (int i = 0; i < 12; ++i) {
            int d = dg*12 + i;
            const float* wdt = dtw + ((size_t)k*D_ + d)*6;
            float acc = dtb[k*D_ + d];
            #pragma unroll
            for (int rr = 0; rr < 6; ++rr) acc = fmaf(r[rr], wdt[rr], acc);
            float sp = fmaxf(acc, 0.f) + log1pf(__expf(-fabsf(acc)));
            dout[(size_t)d*L_ + l0 + l] = sp;
        }
    }
    {   // Bs/Cs -> (b,k,l,n): lane n coalesced (128B per row pair)
        float* Bsp = ws + OFF_BS + ((size_t)(b*K_ + k)*L_ + l0)*NS;
        float* Csp = ws + OFF_CS + ((size_t)(b*K_ + k)*L_ + l0)*NS;
        int n = tid & 31, lq = tid >> 5;
        #pragma unroll
        for (int j = 0; j < 2; ++j) {
            int ll = lq + 8*j;
            Bsp[(size_t)ll*NS + n] = xd[(RK + n)*17 + ll];
            Csp[(size_t)ll*NS + n] = xd[(RK + NS + n)*17 + ll];
        }
    }
}

// ---------------- K4a: local chunk scan + in-LDS combine -> H0 --------------
// grid 1536 = bk(8) * d(192); 512 thr = 16 chunks x 32 states; 1 chain/lane
__global__ __launch_bounds__(512) void k4a_local(const float* __restrict__ Alogs,
        float* __restrict__ ws) {
    __shared__ float Pl[NC][NS];
    __shared__ float Hl[NC][NS];
    int blk = blockIdx.x;
    int d = blk % D_;
    int bk = blk / D_;
    int b = bk >> 2, k = bk & 3;
    int c = threadIdx.x >> 5;
    int n = threadIdx.x & 31;
    float a2 = -__expf(Alogs[((size_t)k*D_ + d)*NS + n]) * LOG2E;
    const float* dptr = ws + OFF_DELTA + (size_t)(bk*D_ + d)*L_ + c*CL;
    const float* ubase = ws + ((k & 1) ? OFF_XWH : OFF_XHW) + (size_t)(b*D_ + d)*L_;
    const float* Bsp = ws + OFF_BS + ((size_t)bk*L_ + c*CL)*NS;
    bool flip = (k >= 2);
    float h = 0.f, sd = 0.f;
    for (int lb = 0; lb < CL; lb += 4) {
        float4 d4 = *(const float4*)(dptr + lb);
        float4 t4;
        if (!flip) {
            t4 = *(const float4*)(ubase + c*CL + lb);
        } else {
            float4 r = *(const float4*)(ubase + (L_ - 4) - (c*CL + lb));
            t4 = make_float4(r.w, r.z, r.y, r.x);
        }
        float dl[4] = {d4.x, d4.y, d4.z, d4.w};
        float uu[4] = {t4.x, t4.y, t4.z, t4.w};
        #pragma unroll
        for (int j = 0; j < 4; ++j) {
            float bn = Bsp[(lb + j)*NS + n];   // lane-coalesced 128B
            float e = fexp2(dl[j]*a2);
            h = fmaf(h, e, dl[j]*uu[j]*bn);
            sd += dl[j];
        }
    }
    Pl[c][n] = fexp2(a2*sd);   // product of dA over chunk == exp(a * sum delta)
    Hl[c][n] = h;
    __syncthreads();
    if (threadIdx.x < NS) {    // serial combine over chunks; n = threadIdx.x
        float hh = 0.f;
        #pragma unroll
        for (int cc = 0; cc < NC; ++cc) {
            float p  = Pl[cc][n];
            float hf = Hl[cc][n];
            Pl[cc][n] = hh;    // overwrite with h0 for chunk cc
            hh = fmaf(hh, p, hf);
        }
    }
    __syncthreads();
    // coalesced H0 write: layout (chain, c, n), linear in tid
    ws[OFF_H0 + (size_t)(bk*D_ + d)*NC*NS + threadIdx.x] = Pl[c][n];
}

// ---------------- K4c: replay from true h0; batch-4 reduce; coalesced write -
// grid 1536 = bk(8) * c(16) * dg(12); 512 thr = 16 subwaves(d) x 32 states
__global__ __launch_bounds__(512) void k4c_scan(const float* __restrict__ Alogs,
        const float* __restrict__ Dsp, float* __restrict__ ws) {
    __shared__ float yld[CL*17];     // [l][d], stride 17 -> conflict-free
    int blk = blockIdx.x;
    int dg = blk % 12;
    int c  = (blk / 12) % NC;
    int bk = blk / (12*NC);
    int b = bk >> 2, k = bk & 3;
    int sw = threadIdx.x >> 5;
    int n  = threadIdx.x & 31;
    int d = dg*16 + sw;
    float a2 = -__expf(Alogs[((size_t)k*D_ + d)*NS + n]) * LOG2E;
    float dc32 = Dsp[k*D_ + d] * (1.f/32.f);
    const float* dptr = ws + OFF_DELTA + (size_t)(bk*D_ + d)*L_ + c*CL;
    const float* ubase = ws + ((k & 1) ? OFF_XWH : OFF_XHW) + (size_t)(b*D_ + d)*L_;
    const float* Bsp = ws + OFF_BS + ((size_t)bk*L_ + c*CL)*NS;
    const float* Csp = ws + OFF_CS + ((size_t)bk*L_ + c*CL)*NS;
    bool flip = (k >= 2);
    float h = ws[OFF_H0 + (size_t)(bk*D_ + d)*NC*NS + c*NS + n];
    int g = n >> 3;
    int off = ((g & 1) << 1) | (g >> 1);   // lane-group -> l-offset [0,2,1,3]
    for (int lb = 0; lb < CL; lb += 4) {
        float4 d4 = *(const float4*)(dptr + lb);
        float4 t4;
        if (!flip) {
            t4 = *(const float4*)(ubase + c*CL + lb);
        } else {
            float4 r = *(const float4*)(ubase + (L_ - 4) - (c*CL + lb));
            t4 = make_float4(r.w, r.z, r.y, r.x);
        }
        float dl[4] = {d4.x, d4.y, d4.z, d4.w};
        float uu[4] = {t4.x, t4.y, t4.z, t4.w};
        float y[4];
        #pragma unroll
        for (int j = 0; j < 4; ++j) {
            float bn = Bsp[(lb + j)*NS + n];   // lane-coalesced 128B
            float cn = Csp[(lb + j)*NS + n];
            float e = fexp2(dl[j]*a2);
            h = fmaf(h, e, dl[j]*uu[j]*bn);
            // D*u/32 folded into every lane's y: 32-lane tree-sum restores D*u
            y[j] = fmaf(h, cn, dc32*uu[j]);
        }
        // shared butterfly: 4 values reduced across 32 lanes
        #pragma unroll
        for (int j = 0; j < 4; ++j) y[j] += __shfl_xor(y[j], 16);
        float z0 = (n & 16) ? y[1] : y[0];
        float z1 = (n & 16) ? y[3] : y[2];
        z0 += __shfl_xor(z0, 8);
        z1 += __shfl_xor(z1, 8);
        float wv = (n & 8) ? z1 : z0;
        wv += __shfl_xor(wv, 4);
        wv += __shfl_xor(wv, 2);
        wv += __shfl_xor(wv, 1);
        if ((n & 7) == 0) yld[(lb + off)*17 + sw] = wv;
    }
    __syncthreads();
    float* ysp = ws + OFF_YS + ((size_t)bk*L_ + c*CL)*D_ + dg*16;
    for (int it = 0; it < 5; ++it) {
        int idx = it*512 + threadIdx.x;
        if (idx < CL*16) {
            int l = idx >> 4, dd = idx & 15;
            ysp[(size_t)l*D_ + dd] = yld[l*17 + dd];
        }
    }
}

// ---------------- K56: merge + LayerNorm + SiLU gate + out_proj + residual --
// grid 288 = b(2) * ltile16(144); 256 thr
__global__ __launch_bounds__(256) void k56_fused(const float* __restrict__ lnw,
        const float* __restrict__ lnb, const float* __restrict__ w,
        const float* __restrict__ xin, float* __restrict__ out,
        const float* __restrict__ ws) {
    __shared__ __align__(16) float YsT[16*196];  // [pos][d], stride 196
    __shared__ float psum[16][17], psq[16][17];
    __shared__ float outT[16*97];
    int blk = blockIdx.x;
    int b = blk / 144;
    int l0 = (blk % 144) * 16;
    int tid = threadIdx.x;
    {   // phase A: 16 pos x 16 dgroups, 12 d each
        int p = tid >> 4, dg = tid & 15;
        int pos = l0 + p;
        int hh = pos / W_, w0 = pos % W_;
        int poswh = w0*H_ + hh;
        const float* ysb = ws + OFF_YS + (size_t)b*K_*L_*D_;
        const float* r0 = ysb + (size_t)(0*L_ + pos)*D_;
        const float* r1 = ysb + (size_t)(1*L_ + poswh)*D_;
        const float* r2 = ysb + (size_t)(2*L_ + (L_-1-pos))*D_;
        const float* r3 = ysb + (size_t)(3*L_ + (L_-1-poswh))*D_;
        float yv[12];
        float s = 0.f, sq = 0.f;
        #pragma unroll
        for (int i = 0; i < 12; i += 4) {
            int d = dg*12 + i;
            float4 v0 = *(const float4*)(r0 + d);
            float4 v1 = *(const float4*)(r1 + d);
            float4 v2 = *(const float4*)(r2 + d);
            float4 v3 = *(const float4*)(r3 + d);
            float y0 = v0.x+v1.x+v2.x+v3.x;
            float y1 = v0.y+v1.y+v2.y+v3.y;
            float y2 = v0.z+v1.z+v2.z+v3.z;
            float y3 = v0.w+v1.w+v2.w+v3.w;
            yv[i]=y0; yv[i+1]=y1; yv[i+2]=y2; yv[i+3]=y3;
            s += y0+y1+y2+y3;
            sq += y0*y0+y1*y1+y2*y2+y3*y3;
        }
        psum[p][dg] = s; psq[p][dg] = sq;
        __syncthreads();
        float su = 0.f, ssq = 0.f;
        #pragma unroll
        for (int j = 0; j < 16; ++j) { su += psum[p][j]; ssq += psq[p][j]; }
        float mu  = su * (1.f/192.f);
        float var = ssq * (1.f/192.f) - mu*mu;
        float rs  = rsqrtf(var + 1e-5f);
        const float* zp = ws + OFF_Z + (size_t)(b*L_ + pos)*D_;
        #pragma unroll
        for (int i = 0; i < 12; i += 4) {
            int d = dg*12 + i;
            float4 o;
            float* oo = (float*)&o;
            #pragma unroll
            for (int jj = 0; jj < 4; ++jj) {
                float yn = (yv[i+jj] - mu)*rs*lnw[d+jj] + lnb[d+jj];
                float zv = zp[d+jj];
                float sz = zv / (1.f + __expf(-zv));
                oo[jj] = yn * sz;
            }
            *(float4*)&YsT[p*196 + d] = o;
        }
    }
    __syncthreads();
    {   // phase B: GEMM 16 l x 96 c, acc[6] per thread
        int l = tid & 15, cg = tid >> 4;
        float acc[6] = {0.f,0.f,0.f,0.f,0.f,0.f};
        const float4* wp[6];
        #pragma unroll
        for (int i = 0; i < 6; ++i)
            wp[i] = (const float4*)(w + (size_t)(cg*6 + i)*D_);
        for (int q = 0; q < 48; ++q) {
            float4 xr = *(const float4*)&YsT[l*196 + q*4];
            #pragma unroll
            for (int i = 0; i < 6; ++i) {
                float4 wv = wp[i][q];
                acc[i] += xr.x*wv.x + xr.y*wv.y + xr.z*wv.z + xr.w*wv.w;
            }
        }
        #pragma unroll
        for (int i = 0; i < 6; ++i) outT[l*97 + cg*6 + i] = acc[i];
    }
    __syncthreads();
    #pragma unroll
    for (int it = 0; it < 6; ++it) {
        int idx = it*256 + tid;      // 16*96 = 1536
        int p = idx / 96, cc = idx % 96;
        size_t o = (size_t)(b*L_ + l0 + p)*C_ + cc;
        out[o] = xin[o] + outT[p*97 + cc];
    }
}

extern "C" void kernel_launch(void* const* d_in, const int* in_sizes, int n_in,
                              void* d_out, int out_size, void* d_ws, size_t ws_size,
                              hipStream_t stream) {
    const float* x        = (const float*)d_in[0];
    const float* in_proj  = (const float*)d_in[1];
    const float* conv_w   = (const float*)d_in[2];
    const float* conv_b   = (const float*)d_in[3];
    const float* x_proj_w = (const float*)d_in[4];
    const float* dt_w     = (const float*)d_in[5];
    const float* dt_b     = (const float*)d_in[6];
    const float* A_logs   = (const float*)d_in[7];
    const float* Ds       = (const float*)d_in[8];
    const float* ln_w     = (const float*)d_in[9];
    const float* ln_b     = (const float*)d_in[10];
    const float* out_w    = (const float*)d_in[11];
    float* out = (float*)d_out;
    float* ws  = (float*)d_ws;

    k1_inproj <<<576,  256, 0, stream>>>(x, in_proj, ws);
    k2_conv   <<<768,  256, 0, stream>>>(conv_w, conv_b, ws);
    k3_xproj  <<<1152, 256, 0, stream>>>(x_proj_w, dt_w, dt_b, ws);
    k4a_local <<<NCH,  512, 0, stream>>>(A_logs, ws);
    k4c_scan  <<<1536, 512, 0, stream>>>(A_logs, Ds, ws);
    k56_fused <<<288,  256, 0, stream>>>(ln_w, ln_b, out_w, x, out, ws);
}